// Round 6
// baseline (406.191 us; speedup 1.0000x reference)
//
#include <hip/hip_runtime.h>

// LinearAttention (B=16, C=256, 64x64 spatial, 8 heads x 32) -- fp32 in/out, bf16/fp32 internal.
// Workspace map (byte offsets), peak 98 MiB:
//   par0  [0, 528K)              fp32 [128][1056]  ctx partials, strip 0 (plain stores, no atomics)
//   wb    [528K, 1040K)          bf16 weights: wkv-interleaved (512x256) | wq | wo
//   par1  [1040K, 1568K)         fp32 [128][1056]  ctx partials, strip 1
//   xT    [2 MiB, 34 MiB)        bf16 [16][4096][256]   LN(fmap)*g, transposed
//   kvT   [34 MiB, 98 MiB)       bf16 [16][4096][512]   k/v interleaved: col 2C=k_C, 2C+1=v_C
//                                LIVE during ctx -- nothing may alias it then! (R4 lesson)
//   qT    [34 MiB, 66 MiB)       alias (kvT dead after ctx)
//   ctxF  [34 MiB, 34M+512K)     fp32 [128][1024]  final ctx (written by reduce AFTER dwq; qT dead)
//   ksF   [34M+512K, 34M+528K)   fp32 [128][32]
//   q'    [66 MiB, 98 MiB)       softmaxed q
//   s     [2 MiB, 34 MiB)        silu(attn out)  (xT dead)
//   y     [66 MiB, 98 MiB)       s @ wo^T        (q' dead)
// Order: prep -> ln_tin -> gemm(KV) -> ctx -> gemm(Q) -> dwq -> reduce -> attn -> gemm(O) -> ln_tout

typedef unsigned short u16;
typedef __bf16 bf16x8 __attribute__((ext_vector_type(8)));
typedef float f32x4 __attribute__((ext_vector_type(4)));
typedef float f32x16 __attribute__((ext_vector_type(16)));

#define DEV static __device__ __forceinline__

DEV float b2f(u16 u) { return __uint_as_float(((unsigned int)u) << 16); }
DEV u16 f2bf(float f) {
  unsigned int u = __float_as_uint(f);
  return (u16)((u + 0x7fffu + ((u >> 16) & 1u)) >> 16);  // RNE
}
DEV void gl2lds16(const void* g, void* l) {
  __builtin_amdgcn_global_load_lds((__attribute__((address_space(1))) void*)g,
                                   (__attribute__((address_space(3))) void*)l, 16, 0, 0);
}

// ---------------- prep: fp32 -> bf16 weight conversion (wk/wv row-interleaved) ----------
__global__ __launch_bounds__(256) void prep_kernel(const float* __restrict__ wk,
                                                   const float* __restrict__ wv,
                                                   const float* __restrict__ wq,
                                                   const float* __restrict__ wo,
                                                   u16* __restrict__ wb) {
  const int i = blockIdx.x * 256 + threadIdx.x;  // 0..65535
  const int yb = blockIdx.y;
  if (yb == 0)      wb[(i >> 8) * 512 + (i & 255)] = f2bf(wk[i]);        // row 2r
  else if (yb == 1) wb[(i >> 8) * 512 + 256 + (i & 255)] = f2bf(wv[i]);  // row 2r+1
  else if (yb == 2) wb[131072 + i] = f2bf(wq[i]);
  else              wb[196608 + i] = f2bf(wo[i]);
}

// ---------------- K0: channel-LN + transpose in (fp32 -> bf16) ----------------
__global__ __launch_bounds__(256) void ln_tin_kernel(const float* __restrict__ f,
                                                     const float* __restrict__ g,
                                                     u16* __restrict__ xT) {
  __shared__ u16 tile[64 * 258];
  __shared__ float red[2 * 256];
  __shared__ float mu_s[64], inv_s[64];
  const int t = threadIdx.x;
  const int p0 = blockIdx.x * 64;
  const int b = blockIdx.y;
  const long fb = (long)b * 256 * 4096;
  const int p = t & 63, cg = t >> 6;
  float s1 = 0.f, s2 = 0.f;
  for (int pass = 0; pass < 64; ++pass) {
    int c = pass * 4 + cg;
    float v = f[fb + (long)c * 4096 + p0 + p];
    s1 += v; s2 += v * v;
    tile[p * 258 + c] = f2bf(v);
  }
  red[cg * 64 + p] = s1;
  red[256 + cg * 64 + p] = s2;
  __syncthreads();
  if (t < 64) {
    float a1 = red[t] + red[64 + t] + red[128 + t] + red[192 + t];
    float a2 = red[256 + t] + red[320 + t] + red[384 + t] + red[448 + t];
    float mu = a1 * (1.f / 256.f);
    float var = a2 * (1.f / 256.f) - mu * mu;
    mu_s[t] = mu;
    inv_s[t] = 1.0f / sqrtf(var + 1e-5f);
  }
  __syncthreads();
  {
    float gc = g[t];
    for (int pp = 0; pp < 64; ++pp) {
      float v = b2f(tile[pp * 258 + t]);
      xT[((long)b * 4096 + p0 + pp) * 256 + t] = f2bf((v - mu_s[pp]) * inv_s[pp] * gc);
    }
  }
}

// ---------------- GEMM: C[m][n] = sum_k A[m][k]*Bt[n][k] (MFMA 16x16x32, 128x128 tile) ----
__global__ __launch_bounds__(256) void gemm_bt_kernel(
    const u16* __restrict__ A, const u16* __restrict__ B0, const u16* __restrict__ B1,
    u16* __restrict__ Cg, int ldc, long sA, long sC) {
  __shared__ u16 As[128 * 32];
  __shared__ u16 Bs[128 * 32];
  const int t = threadIdx.x;
  const int wave = t >> 6, lane = t & 63, quad = lane >> 4, l16 = lane & 15;
  const int wr = wave >> 1, wc = wave & 1;
  const int m0 = blockIdx.x * 128;
  const int jt = blockIdx.y;
  const int b = blockIdx.z;
  const u16* Ab = A + (long)b * sA + (long)m0 * 256;
  const u16* Bt = (jt < 2 ? B0 : B1) + (jt & 1) * 128 * 256;
  u16* Cb = Cg + (long)b * sC + (long)m0 * ldc + jt * 128;

  const int srow = lane >> 2;        // staging: row within 16-row chunk
  const int scol = (lane & 3) * 8;   // staging: col (elements)
  f32x4 acc[4][4];
#pragma unroll
  for (int i = 0; i < 4; ++i)
#pragma unroll
    for (int j = 0; j < 4; ++j) acc[i][j] = (f32x4){0.f, 0.f, 0.f, 0.f};

  const int aoff = (wr * 64 + l16) * 32 + quad * 8;
  const int boff = (wc * 64 + l16) * 32 + quad * 8;

  for (int ks = 0; ks < 8; ++ks) {
    const int k0 = ks * 32;
    __syncthreads();
    for (int i = wave; i < 8; i += 4) {
      gl2lds16(Ab + (i * 16 + srow) * 256 + k0 + scol, &As[i * 512 + lane * 8]);
      gl2lds16(Bt + (i * 16 + srow) * 256 + k0 + scol, &Bs[i * 512 + lane * 8]);
    }
    __syncthreads();  // compiler drains vmcnt(0) before s_barrier
    bf16x8 af[4], bfr[4];
#pragma unroll
    for (int mt = 0; mt < 4; ++mt) af[mt] = *(const bf16x8*)&As[aoff + mt * 512];
#pragma unroll
    for (int nt = 0; nt < 4; ++nt) bfr[nt] = *(const bf16x8*)&Bs[boff + nt * 512];
#pragma unroll
    for (int mt = 0; mt < 4; ++mt)
#pragma unroll
      for (int nt = 0; nt < 4; ++nt)
        acc[mt][nt] = __builtin_amdgcn_mfma_f32_16x16x32_bf16(af[mt], bfr[nt], acc[mt][nt], 0, 0, 0);
  }
#pragma unroll
  for (int mt = 0; mt < 4; ++mt) {
    const int mbase = wr * 64 + mt * 16 + quad * 4;
#pragma unroll
    for (int nt = 0; nt < 4; ++nt) {
      const int n = wc * 64 + nt * 16 + l16;
#pragma unroll
      for (int r = 0; r < 4; ++r)
        Cb[(long)(mbase + r) * ldc + n] = f2bf(acc[mt][nt][r]);
    }
  }
}

// ---------------- K2: dwconv(q) + softmax over d + *SCALE (LDS-tiled stencil) ----------
// block = (strip of 4 x-rows, head, batch). Stage ALL 6 needed rows (x0-1..x0+4) of
// [64 y][32 ch] bf16 into LDS (y-padded, row stride 40 u16 = 80 B for bank spread),
// then 9-tap stencil reads are ds_read_b128. Lane owns (y = wave*16 + lane&15, 8 ch).
__global__ __launch_bounds__(256) void dwq_kernel(const u16* __restrict__ qT,
                                                  const float* __restrict__ wdw,
                                                  u16* __restrict__ qp) {
  __shared__ u16 tile[6 * 66 * 40];  // [slot][y+1][ch pad40], 31680 B
  const int t = threadIdx.x;
  const int strip = blockIdx.x, h = blockIdx.y, b = blockIdx.z;
  const int x0 = strip * 4;
  const int wave = t >> 6, lane = t & 63;
  const int ysel = lane & 15, cg = lane >> 4;
  const int y = wave * 16 + ysel;
  const int ty = t >> 2, tc = t & 3;  // staging: y-row, ch-quarter

  // zero y-borders (rows 0 and 65 of each slot)
  if (t < 48) {
    const int slot = t >> 3, brd = (t >> 2) & 1, c4 = t & 3;
    *(uint4*)&tile[slot * 2640 + (brd ? 65 * 40 : 0) + c4 * 8] = (uint4){0, 0, 0, 0};
  }
  // stage rows x0-1 .. x0+4 (zeros when out of range)
  const u16* qrow = qT + (long)b * 4096 * 256 + h * 32 + tc * 8;
#pragma unroll
  for (int s = 0; s < 6; ++s) {
    const int xx = x0 - 1 + s;
    uint4 v = (uint4){0, 0, 0, 0};
    if ((unsigned)xx < 64u) v = *(const uint4*)(qrow + (long)(xx * 64 + ty) * 256);
    *(uint4*)&tile[s * 2640 + (ty + 1) * 40 + tc * 8] = v;
  }
  float w[72];
#pragma unroll
  for (int q = 0; q < 8; ++q)
#pragma unroll
    for (int i = 0; i < 9; ++i) w[q * 9 + i] = wdw[(h * 32 + cg * 8 + q) * 9 + i];
  __syncthreads();

  u16* ob = qp + ((long)b * 4096 + y) * 256 + h * 32 + cg * 8;
#pragma unroll
  for (int it = 0; it < 4; ++it) {
    const int x = x0 + it;
    float acc[8] = {0.f, 0.f, 0.f, 0.f, 0.f, 0.f, 0.f, 0.f};
#pragma unroll
    for (int r = 0; r < 3; ++r) {
#pragma unroll
      for (int dy = 0; dy < 3; ++dy) {
        uint4 pk = *(const uint4*)&tile[(it + r) * 2640 + (y + dy) * 40 + cg * 8];
        const u16* s = (const u16*)&pk;
#pragma unroll
        for (int q = 0; q < 8; ++q)
          acc[q] = fmaf(w[q * 9 + r * 3 + dy], b2f(s[q]), acc[q]);
      }
    }
    float e[8];
    float s = 0.f;
#pragma unroll
    for (int q = 0; q < 8; ++q) { e[q] = __expf(acc[q]); s += e[q]; }
    s += __shfl_xor(s, 16);
    s += __shfl_xor(s, 32);
    const float inv = 0.17677669529663687f / s;  // SCALE / sum
    uint4 o;
    u16* os = (u16*)&o;
#pragma unroll
    for (int q = 0; q < 8; ++q) os[q] = f2bf(e[q] * inv);
    *(uint4*)(ob + (long)x * 16384) = o;
  }
}

// ---------------- K3: dwconv(k,v)+exp + Gram via 32x32x16 MFMA (prefetched streamer) ----
// block = (strip of 32 x-rows, head, batch), 1024 threads = 16 waves:
//   group g = wave>>2 owns 8 x-rows, wq = wave&3 owns a 16-y quarter; lane owns channel
//   c = lane&31, 8-y run (half = lane>>5). kvT is k/v-interleaved: one 4 B load yields
//   both k and v. DIST-1 PREFETCH: at top of iteration it, issue loads for row x+2
//   into ft* (used only next iteration); the ~600-cycle stencil+MFMA hides the latency.
//   NO ATOMICS: 3-round LDS wave-tree reduce, wave 0 stores the 1056-float partial.
__global__ __launch_bounds__(1024, 4) void ctx_kernel(const u16* __restrict__ kvT,
                                                      const float* __restrict__ wkdw,
                                                      const float* __restrict__ wvdw,
                                                      float* __restrict__ par0,
                                                      float* __restrict__ par1) {
  __shared__ float redb[8 * 1088];  // 34816 B: staging slabs for the wave tree
  __shared__ float redk[16 * 32];   // per-wave ksum partials
  const int t = threadIdx.x;
  const int strip = blockIdx.x, h = blockIdx.y, b = blockIdx.z;
  const int wave = t >> 6, lane = t & 63;
  const int g = wave >> 2, wq = wave & 3;
  const int x0 = strip * 32 + g * 8;
  const int c = lane & 31, half = lane >> 5;
  const int ystart = wq * 16 + half * 8;
  float wk[9], wv[9];
#pragma unroll
  for (int i = 0; i < 9; ++i) {
    wk[i] = wkdw[(h * 32 + c) * 9 + i];
    wv[i] = wvdw[(h * 32 + c) * 9 + i];
  }
  const u16* kb = kvT + (long)b * 4096 * 512 + 2 * (h * 32 + c);

  float fk[3][10], fv[3][10];   // rows x-1, x, x+1
  float ftk[10], ftv[10];       // prefetch buffer (row x+2)
#pragma unroll
  for (int r = 0; r < 3; ++r) {
    const int x = x0 - 1 + r;
#pragma unroll
    for (int m = 0; m < 10; ++m) {
      const int yy = ystart - 1 + m;
      float a = 0.f, bb = 0.f;
      if (((unsigned)x < 64u) & ((unsigned)yy < 64u)) {
        const unsigned u = *(const unsigned*)(kb + (long)(x * 64 + yy) * 512);
        a = b2f((u16)(u & 0xffffu));
        bb = b2f((u16)(u >> 16));
      }
      fk[r][m] = a; fv[r][m] = bb;
    }
  }
  f32x16 acc;
#pragma unroll
  for (int r = 0; r < 16; ++r) acc[r] = 0.f;
  float ks = 0.f;

#pragma unroll
  for (int it = 0; it < 8; ++it) {
    // 1) prefetch row x+2 (used NEXT iteration) -- issue loads before the compute
    if (it < 7) {
      const int xn = x0 + it + 2;
#pragma unroll
      for (int m = 0; m < 10; ++m) {
        const int yy = ystart - 1 + m;
        float a = 0.f, bb = 0.f;
        if (((unsigned)xn < 64u) & ((unsigned)yy < 64u)) {
          const unsigned u = *(const unsigned*)(kb + (long)(xn * 64 + yy) * 512);
          a = b2f((u16)(u & 0xffffu));
          bb = b2f((u16)(u >> 16));
        }
        ftk[m] = a; ftv[m] = bb;
      }
    }
    // 2) stencil + exp + MFMA on rows already in registers
    union { bf16x8 v; u16 s[8]; } af, bf_;
#pragma unroll
    for (int j = 0; j < 8; ++j) {
      float a = 0.f, bb = 0.f;
#pragma unroll
      for (int r = 0; r < 3; ++r)
#pragma unroll
        for (int dy = 0; dy < 3; ++dy) {
          a = fmaf(wk[r * 3 + dy], fk[r][j + dy], a);
          bb = fmaf(wv[r * 3 + dy], fv[r][j + dy], bb);
        }
      const u16 eb = f2bf(__expf(a));
      ks += b2f(eb);
      af.s[j] = eb;
      bf_.s[j] = f2bf(bb);
    }
    acc = __builtin_amdgcn_mfma_f32_32x32x16_bf16(af.v, bf_.v, acc, 0, 0, 0);
    // 3) shift window (prefetched row becomes x+1)
#pragma unroll
    for (int m = 0; m < 10; ++m) {
      fk[0][m] = fk[1][m]; fk[1][m] = fk[2][m]; fk[2][m] = ftk[m];
      fv[0][m] = fv[1][m]; fv[1][m] = fv[2][m]; fv[2][m] = ftv[m];
    }
  }
  // ksum: combine y-halves (same c), stage per wave
  ks += __shfl_xor(ks, 32);
  if (half == 0) redk[wave * 32 + c] = ks;
  // 3-round tree reduction of the 16 wave accumulators (LDS stays at 8 slabs):
  if (wave >= 8) {
#pragma unroll
    for (int r = 0; r < 16; ++r) redb[(wave - 8) * 1088 + lane * 17 + r] = acc[r];
  }
  __syncthreads();
  if (wave < 8) {
#pragma unroll
    for (int r = 0; r < 16; ++r) acc[r] += redb[wave * 1088 + lane * 17 + r];
  }
  __syncthreads();
  if (wave >= 4 && wave < 8) {
#pragma unroll
    for (int r = 0; r < 16; ++r) redb[(wave - 4) * 1088 + lane * 17 + r] = acc[r];
  }
  __syncthreads();
  if (wave < 4) {
#pragma unroll
    for (int r = 0; r < 16; ++r) acc[r] += redb[wave * 1088 + lane * 17 + r];
  }
  __syncthreads();
  if (wave >= 1 && wave < 4) {
#pragma unroll
    for (int r = 0; r < 16; ++r) redb[(wave - 1) * 1088 + lane * 17 + r] = acc[r];
  }
  __syncthreads();
  if (wave == 0) {
    float* par = (strip ? par1 : par0) + (long)(b * 8 + h) * 1056;
#pragma unroll
    for (int r = 0; r < 16; ++r) {
      float sum = acc[r] + redb[lane * 17 + r] + redb[1088 + lane * 17 + r] +
                  redb[2176 + lane * 17 + r];
      const int d = (r & 3) + 8 * (r >> 2) + 4 * half;  // C/D row map [m74/m101]
      par[d * 32 + c] = sum;  // plain coalesced store -- no atomic
    }
    if (t < 32) {
      float s = 0.f;
#pragma unroll
      for (int w = 0; w < 16; ++w) s += redk[w * 32 + t];
      par[1024 + t] = s;
    }
  }
}

// ---------------- K3b: sum the 2 strip-partials -> final ctx + ksum ----------------
__global__ __launch_bounds__(256) void reduce_kernel(const float* __restrict__ par0,
                                                     const float* __restrict__ par1,
                                                     float* __restrict__ ctxF,
                                                     float* __restrict__ ksF) {
  const int bh = blockIdx.x;
  const long base = (long)bh * 1056;
  for (int i = threadIdx.x; i < 1056; i += 256) {
    float v = par0[base + i] + par1[base + i];
    if (i < 1024) ctxF[(long)bh * 1024 + i] = v;
    else ksF[(long)bh * 32 + (i - 1024)] = v;
  }
}

// ---------------- K4: s = silu(q' @ (ctx/ksum)) via MFMA 16x16x32 ----------------
// block = (128-row tile, head-pair, batch), 256 threads = 4 waves x 32 rows.
// Prologue: cnT[hh][e][d] = ctx/ksum for the pair's 2 heads, bf16 hi+lo split in LDS.
// Main: per head, per 16-row tile: A-frag straight from global q' (16 B/lane),
// D = A*cn_lo + A*cn_hi (chained MFMA, fp32-accurate cn). Epilogue: silu + store.
__global__ __launch_bounds__(256) void attn_kernel(const u16* __restrict__ qp,
                                                   const float* __restrict__ ctxg,
                                                   const float* __restrict__ ksumg,
                                                   u16* __restrict__ sout) {
  __shared__ u16 cnhi[2 * 32 * 40];  // [hh][e][d], 5120 B
  __shared__ u16 cnlo[2 * 32 * 40];
  const int t = threadIdx.x;
  const int p0 = blockIdx.x * 128;
  const int hp = blockIdx.y;  // head pair
  const int b = blockIdx.z;
  const int wave = t >> 6, lane = t & 63, quad = lane >> 4, l16 = lane & 15;

  // normalize ctx (2 heads), split hi/lo, transpose to [e][d]
  for (int j = 0; j < 8; ++j) {
    const int lidx = j * 256 + t;  // [0,2048)
    const int e = lidx & 31, d = (lidx >> 5) & 31, hh = lidx >> 10;
    const int gd = (hp * 2 + hh) * 32 + d;  // global d-row in [0,256)
    const float c = ctxg[(long)b * 8192 + gd * 32 + e] / ksumg[(long)b * 256 + gd];
    const u16 hi = f2bf(c);
    cnhi[hh * 1280 + e * 40 + d] = hi;
    cnlo[hh * 1280 + e * 40 + d] = f2bf(c - b2f(hi));
  }
  __syncthreads();

  const u16* qb = qp + ((long)b * 4096 + p0 + wave * 32) * 256;
  u16* ob = sout + ((long)b * 4096 + p0 + wave * 32) * 256;
#pragma unroll
  for (int hh = 0; hh < 2; ++hh) {
    const int h = hp * 2 + hh;
    const int cb = hh * 1280 + quad * 8;
    const bf16x8 bhi0 = *(const bf16x8*)&cnhi[cb + l16 * 40];
    const bf16x8 bhi1 = *(const bf16x8*)&cnhi[cb + (16 + l16) * 40];
    const bf16x8 blo0 = *(const bf16x8*)&cnlo[cb + l16 * 40];
    const bf16x8 blo1 = *(const bf16x8*)&cnlo[cb + (16 + l16) * 40];
#pragma unroll
    for (int rt = 0; rt < 2; ++rt) {
      const bf16x8 af = *(const bf16x8*)&qb[(rt * 16 + l16) * 256 + h * 32 + quad * 8];
      f32x4 a0 = (f32x4){0.f, 0.f, 0.f, 0.f};
      f32x4 a1 = (f32x4){0.f, 0.f, 0.f, 0.f};
      a0 = __builtin_amdgcn_mfma_f32_16x16x32_bf16(af, blo0, a0, 0, 0, 0);
      a0 = __builtin_amdgcn_mfma_f32_16x16x32_bf16(af, bhi0, a0, 0, 0, 0);
      a1 = __builtin_amdgcn_mfma_f32_16x16x32_bf16(af, blo1, a1, 0, 0, 0);
      a1 = __builtin_amdgcn_mfma_f32_16x16x32_bf16(af, bhi1, a1, 0, 0, 0);
#pragma unroll
      for (int r = 0; r < 4; ++r) {
        const int row = rt * 16 + quad * 4 + r;
        const float v0 = a0[r], v1 = a1[r];
        ob[(long)row * 256 + h * 32 + l16] = f2bf(v0 / (1.f + __expf(-v0)));
        ob[(long)row * 256 + h * 32 + 16 + l16] = f2bf(v1 / (1.f + __expf(-v1)));
      }
    }
  }
}

// ---------------- K6: channel-LN + transpose out (bf16 -> fp32) ----------------
__global__ __launch_bounds__(256) void ln_tout_kernel(const u16* __restrict__ y,
                                                      const float* __restrict__ gout,
                                                      float* __restrict__ out) {
  __shared__ u16 tile[64 * 258];
  __shared__ float red[2 * 256];
  __shared__ float mu_s[64], inv_s[64];
  const int t = threadIdx.x;
  const int p0 = blockIdx.x * 64;
  const int b = blockIdx.y;
  for (int p = 0; p < 64; ++p)
    tile[p * 258 + t] = y[((long)b * 4096 + p0 + p) * 256 + t];
  __syncthreads();
  {
    const int p = t & 63, part = t >> 6;
    float s1 = 0.f, s2 = 0.f;
    for (int k = 0; k < 64; ++k) {
      float v = b2f(tile[p * 258 + part * 64 + k]);
      s1 += v; s2 += v * v;
    }
    red[part * 64 + p] = s1;
    red[256 + part * 64 + p] = s2;
  }
  __syncthreads();
  if (t < 64) {
    float s1 = red[t] + red[64 + t] + red[128 + t] + red[192 + t];
    float s2 = red[256 + t] + red[320 + t] + red[384 + t] + red[448 + t];
    float mu = s1 * (1.f / 256.f);
    float var = s2 * (1.f / 256.f) - mu * mu;
    mu_s[t] = mu;
    inv_s[t] = 1.0f / sqrtf(var + 1e-5f);
  }
  __syncthreads();
  {
    const int p = t & 63, cg = t >> 6;
    const long ob = (long)b * 256 * 4096;
    for (int pass = 0; pass < 64; ++pass) {
      int c = pass * 4 + cg;
      float v = b2f(tile[p * 258 + c]);
      out[ob + (long)c * 4096 + p0 + p] = (v - mu_s[p]) * inv_s[p] * gout[c];
    }
  }
}

extern "C" void kernel_launch(void* const* d_in, const int* in_sizes, int n_in,
                              void* d_out, int out_size, void* d_ws, size_t ws_size,
                              hipStream_t stream) {
  (void)in_sizes; (void)n_in; (void)out_size; (void)ws_size;
  const float* fmap = (const float*)d_in[0];
  const float* gnorm = (const float*)d_in[1];
  const float* wq1 = (const float*)d_in[2];
  const float* wqdw = (const float*)d_in[3];
  const float* wk1 = (const float*)d_in[4];
  const float* wkdw = (const float*)d_in[5];
  const float* wv1 = (const float*)d_in[6];
  const float* wvdw = (const float*)d_in[7];
  const float* wo = (const float*)d_in[8];
  const float* gout = (const float*)d_in[9];
  float* out = (float*)d_out;
  char* ws = (char*)d_ws;

  float* par0 = (float*)(ws);                    // [0, 540672)        128*1056*4
  u16* wb = (u16*)(ws + 540672);                 // [528K, 1040K) bf16 wkv|wq|wo
  float* par1 = (float*)(ws + 1064960);          // [1040K, 1568K)
  u16* wkv_bf = wb;                              // interleaved 512x256
  u16* wq_bf = wb + 131072;
  u16* wo_bf = wb + 196608;
  u16* xT = (u16*)(ws + 2097152);                // [2, 34) MiB
  u16* kvT = (u16*)(ws + 35651584);              // [34, 98) MiB -- live through ctx
  u16* qT = kvT;                                 // alias (kvT dead after ctx)
  float* ctxF = (float*)(ws + 35651584);         // alias (qT dead after dwq; reduce runs then)
  float* ksF = (float*)(ws + 35651584 + 524288);
  u16* qp = (u16*)(ws + 69206016);               // [66, 98) MiB (written only after ctx)
  u16* sbuf = xT;                                // alias (xT dead after Q gemm)
  u16* ybuf = qp;                                // alias (qp dead after attn)

  prep_kernel<<<dim3(256, 4), 256, 0, stream>>>(wk1, wv1, wq1, wo, wb);
  ln_tin_kernel<<<dim3(64, 16), 256, 0, stream>>>(fmap, gnorm, xT);
  // KV interleaved: col 2C = k_C, col 2C+1 = v_C (wkv rows interleaved by prep)
  gemm_bt_kernel<<<dim3(32, 4, 16), 256, 0, stream>>>(xT, wkv_bf, wkv_bf + 65536, kvT, 512,
                                                      4096L * 256, 4096L * 512);
  ctx_kernel<<<dim3(2, 8, 16), 1024, 0, stream>>>(kvT, wkdw, wvdw, par0, par1);
  // Q
  gemm_bt_kernel<<<dim3(32, 2, 16), 256, 0, stream>>>(xT, wq_bf, wq_bf, qT, 256,
                                                      4096L * 256, 4096L * 256);
  dwq_kernel<<<dim3(16, 8, 16), 256, 0, stream>>>(qT, wqdw, qp);
  // partials -> final ctx/ksum (placed in dead qT space; must run after dwq)
  reduce_kernel<<<dim3(128), 256, 0, stream>>>(par0, par1, ctxF, ksF);
  attn_kernel<<<dim3(32, 4, 16), 256, 0, stream>>>(qp, ctxF, ksF, sbuf);
  // O
  gemm_bt_kernel<<<dim3(32, 2, 16), 256, 0, stream>>>(sbuf, wo_bf, wo_bf, ybuf, 256,
                                                      4096L * 256, 4096L * 256);
  ln_tout_kernel<<<dim3(64, 16), 256, 0, stream>>>(ybuf, gout, out);
}

// Round 7
// 311.831 us; speedup vs baseline: 1.3026x; 1.3026x over previous
//
#include <hip/hip_runtime.h>

// LinearAttention (B=16, C=256, 64x64 spatial, 8 heads x 32) -- fp32 in/out, bf16/fp32 internal.
// Workspace map (byte offsets), peak 98 MiB:
//   par0  [0, 528K)              fp32 [128][1056]  ctx partials, strip 0 (plain stores, no atomics)
//   wb    [528K, 1040K)          bf16 weights: wkv-interleaved (512x256) | wq | wo
//   par1  [1040K, 1568K)         fp32 [128][1056]  ctx partials, strip 1
//   xT    [2 MiB, 34 MiB)        bf16 [16][4096][256]   LN(fmap)*g, transposed
//   kvT   [34 MiB, 98 MiB)       bf16 [16][4096][512]   k/v interleaved: col 2C=k_C, 2C+1=v_C
//                                LIVE during ctx -- nothing may alias it then! (R4 lesson)
//   qT    [34 MiB, 66 MiB)       alias (kvT dead after ctx)
//   ctxF  [34 MiB, 34M+512K)     fp32 [128][1024]  final ctx (written by reduce AFTER dwq; qT dead)
//   ksF   [34M+512K, 34M+528K)   fp32 [128][32]
//   q'    [66 MiB, 98 MiB)       softmaxed q
//   s     [2 MiB, 34 MiB)       silu(attn out)  (xT dead)
//   y     [66 MiB, 98 MiB)       s @ wo^T        (q' dead)
// Order: prep -> ln_tin -> gemm(KV) -> ctx -> gemm(Q) -> dwq -> reduce -> attn -> gemm(O) -> ln_tout
// R6 lesson: ctx is register-critical. +20 floats of prefetch buffer -> scratch spill
// (FETCH/WRITE +158 MB, 3x slowdown). This version prefetches PACKED u32 (+10 regs only).

typedef unsigned short u16;
typedef __bf16 bf16x8 __attribute__((ext_vector_type(8)));
typedef float f32x4 __attribute__((ext_vector_type(4)));
typedef float f32x16 __attribute__((ext_vector_type(16)));

#define DEV static __device__ __forceinline__

DEV float b2f(u16 u) { return __uint_as_float(((unsigned int)u) << 16); }
DEV u16 f2bf(float f) {
  unsigned int u = __float_as_uint(f);
  return (u16)((u + 0x7fffu + ((u >> 16) & 1u)) >> 16);  // RNE
}
DEV void gl2lds16(const void* g, void* l) {
  __builtin_amdgcn_global_load_lds((__attribute__((address_space(1))) void*)g,
                                   (__attribute__((address_space(3))) void*)l, 16, 0, 0);
}

// ---------------- prep: fp32 -> bf16 weight conversion (wk/wv row-interleaved) ----------
__global__ __launch_bounds__(256) void prep_kernel(const float* __restrict__ wk,
                                                   const float* __restrict__ wv,
                                                   const float* __restrict__ wq,
                                                   const float* __restrict__ wo,
                                                   u16* __restrict__ wb) {
  const int i = blockIdx.x * 256 + threadIdx.x;  // 0..65535
  const int yb = blockIdx.y;
  if (yb == 0)      wb[(i >> 8) * 512 + (i & 255)] = f2bf(wk[i]);        // row 2r
  else if (yb == 1) wb[(i >> 8) * 512 + 256 + (i & 255)] = f2bf(wv[i]);  // row 2r+1
  else if (yb == 2) wb[131072 + i] = f2bf(wq[i]);
  else              wb[196608 + i] = f2bf(wo[i]);
}

// ---------------- K0: channel-LN + transpose in (fp32 -> bf16) ----------------
__global__ __launch_bounds__(256) void ln_tin_kernel(const float* __restrict__ f,
                                                     const float* __restrict__ g,
                                                     u16* __restrict__ xT) {
  __shared__ u16 tile[64 * 258];
  __shared__ float red[2 * 256];
  __shared__ float mu_s[64], inv_s[64];
  const int t = threadIdx.x;
  const int p0 = blockIdx.x * 64;
  const int b = blockIdx.y;
  const long fb = (long)b * 256 * 4096;
  const int p = t & 63, cg = t >> 6;
  float s1 = 0.f, s2 = 0.f;
  for (int pass = 0; pass < 64; ++pass) {
    int c = pass * 4 + cg;
    float v = f[fb + (long)c * 4096 + p0 + p];
    s1 += v; s2 += v * v;
    tile[p * 258 + c] = f2bf(v);
  }
  red[cg * 64 + p] = s1;
  red[256 + cg * 64 + p] = s2;
  __syncthreads();
  if (t < 64) {
    float a1 = red[t] + red[64 + t] + red[128 + t] + red[192 + t];
    float a2 = red[256 + t] + red[320 + t] + red[384 + t] + red[448 + t];
    float mu = a1 * (1.f / 256.f);
    float var = a2 * (1.f / 256.f) - mu * mu;
    mu_s[t] = mu;
    inv_s[t] = 1.0f / sqrtf(var + 1e-5f);
  }
  __syncthreads();
  {
    float gc = g[t];
    for (int pp = 0; pp < 64; ++pp) {
      float v = b2f(tile[pp * 258 + t]);
      xT[((long)b * 4096 + p0 + pp) * 256 + t] = f2bf((v - mu_s[pp]) * inv_s[pp] * gc);
    }
  }
}

// ---------------- GEMM: C[m][n] = sum_k A[m][k]*Bt[n][k] (MFMA 16x16x32, 128x128 tile) ----
__global__ __launch_bounds__(256) void gemm_bt_kernel(
    const u16* __restrict__ A, const u16* __restrict__ B0, const u16* __restrict__ B1,
    u16* __restrict__ Cg, int ldc, long sA, long sC) {
  __shared__ u16 As[128 * 32];
  __shared__ u16 Bs[128 * 32];
  const int t = threadIdx.x;
  const int wave = t >> 6, lane = t & 63, quad = lane >> 4, l16 = lane & 15;
  const int wr = wave >> 1, wc = wave & 1;
  const int m0 = blockIdx.x * 128;
  const int jt = blockIdx.y;
  const int b = blockIdx.z;
  const u16* Ab = A + (long)b * sA + (long)m0 * 256;
  const u16* Bt = (jt < 2 ? B0 : B1) + (jt & 1) * 128 * 256;
  u16* Cb = Cg + (long)b * sC + (long)m0 * ldc + jt * 128;

  const int srow = lane >> 2;        // staging: row within 16-row chunk
  const int scol = (lane & 3) * 8;   // staging: col (elements)
  f32x4 acc[4][4];
#pragma unroll
  for (int i = 0; i < 4; ++i)
#pragma unroll
    for (int j = 0; j < 4; ++j) acc[i][j] = (f32x4){0.f, 0.f, 0.f, 0.f};

  const int aoff = (wr * 64 + l16) * 32 + quad * 8;
  const int boff = (wc * 64 + l16) * 32 + quad * 8;

  for (int ks = 0; ks < 8; ++ks) {
    const int k0 = ks * 32;
    __syncthreads();
    for (int i = wave; i < 8; i += 4) {
      gl2lds16(Ab + (i * 16 + srow) * 256 + k0 + scol, &As[i * 512 + lane * 8]);
      gl2lds16(Bt + (i * 16 + srow) * 256 + k0 + scol, &Bs[i * 512 + lane * 8]);
    }
    __syncthreads();  // compiler drains vmcnt(0) before s_barrier
    bf16x8 af[4], bfr[4];
#pragma unroll
    for (int mt = 0; mt < 4; ++mt) af[mt] = *(const bf16x8*)&As[aoff + mt * 512];
#pragma unroll
    for (int nt = 0; nt < 4; ++nt) bfr[nt] = *(const bf16x8*)&Bs[boff + nt * 512];
#pragma unroll
    for (int mt = 0; mt < 4; ++mt)
#pragma unroll
      for (int nt = 0; nt < 4; ++nt)
        acc[mt][nt] = __builtin_amdgcn_mfma_f32_16x16x32_bf16(af[mt], bfr[nt], acc[mt][nt], 0, 0, 0);
  }
#pragma unroll
  for (int mt = 0; mt < 4; ++mt) {
    const int mbase = wr * 64 + mt * 16 + quad * 4;
#pragma unroll
    for (int nt = 0; nt < 4; ++nt) {
      const int n = wc * 64 + nt * 16 + l16;
#pragma unroll
      for (int r = 0; r < 4; ++r)
        Cb[(long)(mbase + r) * ldc + n] = f2bf(acc[mt][nt][r]);
    }
  }
}

// ---------------- K2: dwconv(q) + softmax over d + *SCALE (LDS-tiled stencil) ----------
// block = (strip of 4 x-rows, head, batch). Stage ALL 6 needed rows (x0-1..x0+4) of
// [64 y][32 ch] bf16 into LDS (y-padded, row stride 40 u16 = 80 B for bank spread),
// then 9-tap stencil reads are ds_read_b128. Lane owns (y = wave*16 + lane&15, 8 ch).
__global__ __launch_bounds__(256) void dwq_kernel(const u16* __restrict__ qT,
                                                  const float* __restrict__ wdw,
                                                  u16* __restrict__ qp) {
  __shared__ u16 tile[6 * 66 * 40];  // [slot][y+1][ch pad40], 31680 B
  const int t = threadIdx.x;
  const int strip = blockIdx.x, h = blockIdx.y, b = blockIdx.z;
  const int x0 = strip * 4;
  const int wave = t >> 6, lane = t & 63;
  const int ysel = lane & 15, cg = lane >> 4;
  const int y = wave * 16 + ysel;
  const int ty = t >> 2, tc = t & 3;  // staging: y-row, ch-quarter

  // zero y-borders (rows 0 and 65 of each slot)
  if (t < 48) {
    const int slot = t >> 3, brd = (t >> 2) & 1, c4 = t & 3;
    *(uint4*)&tile[slot * 2640 + (brd ? 65 * 40 : 0) + c4 * 8] = (uint4){0, 0, 0, 0};
  }
  // stage rows x0-1 .. x0+4 (zeros when out of range)
  const u16* qrow = qT + (long)b * 4096 * 256 + h * 32 + tc * 8;
#pragma unroll
  for (int s = 0; s < 6; ++s) {
    const int xx = x0 - 1 + s;
    uint4 v = (uint4){0, 0, 0, 0};
    if ((unsigned)xx < 64u) v = *(const uint4*)(qrow + (long)(xx * 64 + ty) * 256);
    *(uint4*)&tile[s * 2640 + (ty + 1) * 40 + tc * 8] = v;
  }
  float w[72];
#pragma unroll
  for (int q = 0; q < 8; ++q)
#pragma unroll
    for (int i = 0; i < 9; ++i) w[q * 9 + i] = wdw[(h * 32 + cg * 8 + q) * 9 + i];
  __syncthreads();

  u16* ob = qp + ((long)b * 4096 + y) * 256 + h * 32 + cg * 8;
#pragma unroll
  for (int it = 0; it < 4; ++it) {
    const int x = x0 + it;
    float acc[8] = {0.f, 0.f, 0.f, 0.f, 0.f, 0.f, 0.f, 0.f};
#pragma unroll
    for (int r = 0; r < 3; ++r) {
#pragma unroll
      for (int dy = 0; dy < 3; ++dy) {
        uint4 pk = *(const uint4*)&tile[(it + r) * 2640 + (y + dy) * 40 + cg * 8];
        const u16* s = (const u16*)&pk;
#pragma unroll
        for (int q = 0; q < 8; ++q)
          acc[q] = fmaf(w[q * 9 + r * 3 + dy], b2f(s[q]), acc[q]);
      }
    }
    float e[8];
    float s = 0.f;
#pragma unroll
    for (int q = 0; q < 8; ++q) { e[q] = __expf(acc[q]); s += e[q]; }
    s += __shfl_xor(s, 16);
    s += __shfl_xor(s, 32);
    const float inv = 0.17677669529663687f / s;  // SCALE / sum
    uint4 o;
    u16* os = (u16*)&o;
#pragma unroll
    for (int q = 0; q < 8; ++q) os[q] = f2bf(e[q] * inv);
    *(uint4*)(ob + (long)x * 16384) = o;
  }
}

// ---------------- K3: dwconv(k,v)+exp + Gram via 32x32x16 MFMA (packed-prefetch streamer)
// block = (strip of 32 x-rows, head, batch), 1024 threads = 16 waves:
//   group g = wave>>2 owns 8 x-rows, wq = wave&3 owns a 16-y quarter; lane owns channel
//   c = lane&31, 8-y run (half = lane>>5). kvT is k/v-interleaved: one 4 B load yields
//   both k and v. Distance-1 prefetch of PACKED u32 only (pk[10], +10 regs -- R6's
//   unpacked +20 spilled to scratch): load row x+2 at top, stencil+MFMA on window
//   (independent of pk), unpack pk during the shift at the bottom.
//   NO ATOMICS: 3-round LDS wave-tree reduce, wave 0 stores the 1056-float partial.
__global__ __launch_bounds__(1024, 4) void ctx_kernel(const u16* __restrict__ kvT,
                                                      const float* __restrict__ wkdw,
                                                      const float* __restrict__ wvdw,
                                                      float* __restrict__ par0,
                                                      float* __restrict__ par1) {
  __shared__ float redb[8 * 1088];  // 34816 B: staging slabs for the wave tree
  __shared__ float redk[16 * 32];   // per-wave ksum partials
  const int t = threadIdx.x;
  const int strip = blockIdx.x, h = blockIdx.y, b = blockIdx.z;
  const int wave = t >> 6, lane = t & 63;
  const int g = wave >> 2, wq = wave & 3;
  const int x0 = strip * 32 + g * 8;
  const int c = lane & 31, half = lane >> 5;
  const int ystart = wq * 16 + half * 8;
  float wk[9], wv[9];
#pragma unroll
  for (int i = 0; i < 9; ++i) {
    wk[i] = wkdw[(h * 32 + c) * 9 + i];
    wv[i] = wvdw[(h * 32 + c) * 9 + i];
  }
  const u16* kb = kvT + (long)b * 4096 * 512 + 2 * (h * 32 + c);

  float fk[3][10], fv[3][10];  // rows x-1, x, x+1 (unpacked)
  unsigned pk[10];             // packed prefetch (row x+2): 10 regs only
#pragma unroll
  for (int r = 0; r < 2; ++r) {
    const int x = x0 - 1 + r;
#pragma unroll
    for (int m = 0; m < 10; ++m) {
      const int yy = ystart - 1 + m;
      float a = 0.f, bb = 0.f;
      if (((unsigned)x < 64u) & ((unsigned)yy < 64u)) {
        const unsigned u = *(const unsigned*)(kb + (long)(x * 64 + yy) * 512);
        a = b2f((u16)(u & 0xffffu));
        bb = b2f((u16)(u >> 16));
      }
      fk[r][m] = a; fv[r][m] = bb;
    }
  }
  // row x0+1 packed, then unpack into window slot 2
#pragma unroll
  for (int m = 0; m < 10; ++m) {
    const int yy = ystart - 1 + m;
    unsigned u = 0;
    if (((unsigned)(x0 + 1) < 64u) & ((unsigned)yy < 64u))
      u = *(const unsigned*)(kb + (long)((x0 + 1) * 64 + yy) * 512);
    pk[m] = u;
  }
#pragma unroll
  for (int m = 0; m < 10; ++m) {
    fk[2][m] = __uint_as_float(pk[m] << 16);
    fv[2][m] = __uint_as_float(pk[m] & 0xffff0000u);
  }
  f32x16 acc;
#pragma unroll
  for (int r = 0; r < 16; ++r) acc[r] = 0.f;
  float ks = 0.f;

  for (int it = 0; it < 8; ++it) {
    // 1) prefetch row x+2 PACKED (first use is step 3 -- full stencil hides latency)
    const int xn = x0 + it + 2;
#pragma unroll
    for (int m = 0; m < 10; ++m) {
      const int yy = ystart - 1 + m;
      unsigned u = 0;
      if (((unsigned)xn < 64u) & ((unsigned)yy < 64u))
        u = *(const unsigned*)(kb + (long)(xn * 64 + yy) * 512);
      pk[m] = u;
    }
    // 2) stencil + exp + MFMA on the unpacked window (independent of pk)
    union { bf16x8 v; u16 s[8]; } af, bf_;
#pragma unroll
    for (int j = 0; j < 8; ++j) {
      float a = 0.f, bb = 0.f;
#pragma unroll
      for (int r = 0; r < 3; ++r)
#pragma unroll
        for (int dy = 0; dy < 3; ++dy) {
          a = fmaf(wk[r * 3 + dy], fk[r][j + dy], a);
          bb = fmaf(wv[r * 3 + dy], fv[r][j + dy], bb);
        }
      const u16 eb = f2bf(__expf(a));
      ks += b2f(eb);
      af.s[j] = eb;
      bf_.s[j] = f2bf(bb);
    }
    acc = __builtin_amdgcn_mfma_f32_32x32x16_bf16(af.v, bf_.v, acc, 0, 0, 0);
    // 3) shift window; unpack prefetched row into slot 2 (bit-identical to b2f lo/hi)
#pragma unroll
    for (int m = 0; m < 10; ++m) {
      fk[0][m] = fk[1][m]; fv[0][m] = fv[1][m];
      fk[1][m] = fk[2][m]; fv[1][m] = fv[2][m];
      fk[2][m] = __uint_as_float(pk[m] << 16);
      fv[2][m] = __uint_as_float(pk[m] & 0xffff0000u);
    }
  }
  // ksum: combine y-halves (same c), stage per wave
  ks += __shfl_xor(ks, 32);
  if (half == 0) redk[wave * 32 + c] = ks;
  // 3-round tree reduction of the 16 wave accumulators (LDS stays at 8 slabs):
  if (wave >= 8) {
#pragma unroll
    for (int r = 0; r < 16; ++r) redb[(wave - 8) * 1088 + lane * 17 + r] = acc[r];
  }
  __syncthreads();
  if (wave < 8) {
#pragma unroll
    for (int r = 0; r < 16; ++r) acc[r] += redb[wave * 1088 + lane * 17 + r];
  }
  __syncthreads();
  if (wave >= 4 && wave < 8) {
#pragma unroll
    for (int r = 0; r < 16; ++r) redb[(wave - 4) * 1088 + lane * 17 + r] = acc[r];
  }
  __syncthreads();
  if (wave < 4) {
#pragma unroll
    for (int r = 0; r < 16; ++r) acc[r] += redb[wave * 1088 + lane * 17 + r];
  }
  __syncthreads();
  if (wave >= 1 && wave < 4) {
#pragma unroll
    for (int r = 0; r < 16; ++r) redb[(wave - 1) * 1088 + lane * 17 + r] = acc[r];
  }
  __syncthreads();
  if (wave == 0) {
    float* par = (strip ? par1 : par0) + (long)(b * 8 + h) * 1056;
#pragma unroll
    for (int r = 0; r < 16; ++r) {
      float sum = acc[r] + redb[lane * 17 + r] + redb[1088 + lane * 17 + r] +
                  redb[2176 + lane * 17 + r];
      const int d = (r & 3) + 8 * (r >> 2) + 4 * half;  // C/D row map [m74/m101]
      par[d * 32 + c] = sum;  // plain coalesced store -- no atomic
    }
    if (t < 32) {
      float s = 0.f;
#pragma unroll
      for (int w = 0; w < 16; ++w) s += redk[w * 32 + t];
      par[1024 + t] = s;
    }
  }
}

// ---------------- K3b: sum the 2 strip-partials -> final ctx + ksum ----------------
__global__ __launch_bounds__(256) void reduce_kernel(const float* __restrict__ par0,
                                                     const float* __restrict__ par1,
                                                     float* __restrict__ ctxF,
                                                     float* __restrict__ ksF) {
  const int bh = blockIdx.x;
  const long base = (long)bh * 1056;
  for (int i = threadIdx.x; i < 1056; i += 256) {
    float v = par0[base + i] + par1[base + i];
    if (i < 1024) ctxF[(long)bh * 1024 + i] = v;
    else ksF[(long)bh * 32 + (i - 1024)] = v;
  }
}

// ---------------- K4: s = silu(q' @ (ctx/ksum)) via MFMA 16x16x32 ----------------
// block = (128-row tile, head-pair, batch), 256 threads = 4 waves x 32 rows.
// Prologue: cnT[hh][e][d] = ctx/ksum for the pair's 2 heads, bf16 hi+lo split in LDS.
// Main: per head, per 16-row tile: A-frag straight from global q' (16 B/lane),
// D = A*cn_lo + A*cn_hi (chained MFMA, fp32-accurate cn). Epilogue: silu + store.
__global__ __launch_bounds__(256) void attn_kernel(const u16* __restrict__ qp,
                                                   const float* __restrict__ ctxg,
                                                   const float* __restrict__ ksumg,
                                                   u16* __restrict__ sout) {
  __shared__ u16 cnhi[2 * 32 * 40];  // [hh][e][d], 5120 B
  __shared__ u16 cnlo[2 * 32 * 40];
  const int t = threadIdx.x;
  const int p0 = blockIdx.x * 128;
  const int hp = blockIdx.y;  // head pair
  const int b = blockIdx.z;
  const int wave = t >> 6, lane = t & 63, quad = lane >> 4, l16 = lane & 15;

  // normalize ctx (2 heads), split hi/lo, transpose to [e][d]
  for (int j = 0; j < 8; ++j) {
    const int lidx = j * 256 + t;  // [0,2048)
    const int e = lidx & 31, d = (lidx >> 5) & 31, hh = lidx >> 10;
    const int gd = (hp * 2 + hh) * 32 + d;  // global d-row in [0,256)
    const float c = ctxg[(long)b * 8192 + gd * 32 + e] / ksumg[(long)b * 256 + gd];
    const u16 hi = f2bf(c);
    cnhi[hh * 1280 + e * 40 + d] = hi;
    cnlo[hh * 1280 + e * 40 + d] = f2bf(c - b2f(hi));
  }
  __syncthreads();

  const u16* qb = qp + ((long)b * 4096 + p0 + wave * 32) * 256;
  u16* ob = sout + ((long)b * 4096 + p0 + wave * 32) * 256;
#pragma unroll
  for (int hh = 0; hh < 2; ++hh) {
    const int h = hp * 2 + hh;
    const int cb = hh * 1280 + quad * 8;
    const bf16x8 bhi0 = *(const bf16x8*)&cnhi[cb + l16 * 40];
    const bf16x8 bhi1 = *(const bf16x8*)&cnhi[cb + (16 + l16) * 40];
    const bf16x8 blo0 = *(const bf16x8*)&cnlo[cb + l16 * 40];
    const bf16x8 blo1 = *(const bf16x8*)&cnlo[cb + (16 + l16) * 40];
#pragma unroll
    for (int rt = 0; rt < 2; ++rt) {
      const bf16x8 af = *(const bf16x8*)&qb[(rt * 16 + l16) * 256 + h * 32 + quad * 8];
      f32x4 a0 = (f32x4){0.f, 0.f, 0.f, 0.f};
      f32x4 a1 = (f32x4){0.f, 0.f, 0.f, 0.f};
      a0 = __builtin_amdgcn_mfma_f32_16x16x32_bf16(af, blo0, a0, 0, 0, 0);
      a0 = __builtin_amdgcn_mfma_f32_16x16x32_bf16(af, bhi0, a0, 0, 0, 0);
      a1 = __builtin_amdgcn_mfma_f32_16x16x32_bf16(af, blo1, a1, 0, 0, 0);
      a1 = __builtin_amdgcn_mfma_f32_16x16x32_bf16(af, bhi1, a1, 0, 0, 0);
#pragma unroll
      for (int r = 0; r < 4; ++r) {
        const int row = rt * 16 + quad * 4 + r;
        const float v0 = a0[r], v1 = a1[r];
        ob[(long)row * 256 + h * 32 + l16] = f2bf(v0 / (1.f + __expf(-v0)));
        ob[(long)row * 256 + h * 32 + 16 + l16] = f2bf(v1 / (1.f + __expf(-v1)));
      }
    }
  }
}

// ---------------- K6: channel-LN + transpose out (bf16 -> fp32) ----------------
__global__ __launch_bounds__(256) void ln_tout_kernel(const u16* __restrict__ y,
                                                      const float* __restrict__ gout,
                                                      float* __restrict__ out) {
  __shared__ u16 tile[64 * 258];
  __shared__ float red[2 * 256];
  __shared__ float mu_s[64], inv_s[64];
  const int t = threadIdx.x;
  const int p0 = blockIdx.x * 64;
  const int b = blockIdx.y;
  for (int p = 0; p < 64; ++p)
    tile[p * 258 + t] = y[((long)b * 4096 + p0 + p) * 256 + t];
  __syncthreads();
  {
    const int p = t & 63, part = t >> 6;
    float s1 = 0.f, s2 = 0.f;
    for (int k = 0; k < 64; ++k) {
      float v = b2f(tile[p * 258 + part * 64 + k]);
      s1 += v; s2 += v * v;
    }
    red[part * 64 + p] = s1;
    red[256 + part * 64 + p] = s2;
  }
  __syncthreads();
  if (t < 64) {
    float s1 = red[t] + red[64 + t] + red[128 + t] + red[192 + t];
    float s2 = red[256 + t] + red[320 + t] + red[384 + t] + red[448 + t];
    float mu = s1 * (1.f / 256.f);
    float var = s2 * (1.f / 256.f) - mu * mu;
    mu_s[t] = mu;
    inv_s[t] = 1.0f / sqrtf(var + 1e-5f);
  }
  __syncthreads();
  {
    const int p = t & 63, cg = t >> 6;
    const long ob = (long)b * 256 * 4096;
    for (int pass = 0; pass < 64; ++pass) {
      int c = pass * 4 + cg;
      float v = b2f(tile[p * 258 + c]);
      out[ob + (long)c * 4096 + p0 + p] = (v - mu_s[p]) * inv_s[p] * gout[c];
    }
  }
}

extern "C" void kernel_launch(void* const* d_in, const int* in_sizes, int n_in,
                              void* d_out, int out_size, void* d_ws, size_t ws_size,
                              hipStream_t stream) {
  (void)in_sizes; (void)n_in; (void)out_size; (void)ws_size;
  const float* fmap = (const float*)d_in[0];
  const float* gnorm = (const float*)d_in[1];
  const float* wq1 = (const float*)d_in[2];
  const float* wqdw = (const float*)d_in[3];
  const float* wk1 = (const float*)d_in[4];
  const float* wkdw = (const float*)d_in[5];
  const float* wv1 = (const float*)d_in[6];
  const float* wvdw = (const float*)d_in[7];
  const float* wo = (const float*)d_in[8];
  const float* gout = (const float*)d_in[9];
  float* out = (float*)d_out;
  char* ws = (char*)d_ws;

  float* par0 = (float*)(ws);                    // [0, 540672)        128*1056*4
  u16* wb = (u16*)(ws + 540672);                 // [528K, 1040K) bf16 wkv|wq|wo
  float* par1 = (float*)(ws + 1064960);          // [1040K, 1568K)
  u16* wkv_bf = wb;                              // interleaved 512x256
  u16* wq_bf = wb + 131072;
  u16* wo_bf = wb + 196608;
  u16* xT = (u16*)(ws + 2097152);                // [2, 34) MiB
  u16* kvT = (u16*)(ws + 35651584);              // [34, 98) MiB -- live through ctx
  u16* qT = kvT;                                 // alias (kvT dead after ctx)
  float* ctxF = (float*)(ws + 35651584);         // alias (qT dead after dwq; reduce runs then)
  float* ksF = (float*)(ws + 35651584 + 524288);
  u16* qp = (u16*)(ws + 69206016);               // [66, 98) MiB (written only after ctx)
  u16* sbuf = xT;                                // alias (xT dead after Q gemm)
  u16* ybuf = qp;                                // alias (qp dead after attn)

  prep_kernel<<<dim3(256, 4), 256, 0, stream>>>(wk1, wv1, wq1, wo, wb);
  ln_tin_kernel<<<dim3(64, 16), 256, 0, stream>>>(fmap, gnorm, xT);
  // KV interleaved: col 2C = k_C, col 2C+1 = v_C (wkv rows interleaved by prep)
  gemm_bt_kernel<<<dim3(32, 4, 16), 256, 0, stream>>>(xT, wkv_bf, wkv_bf + 65536, kvT, 512,
                                                      4096L * 256, 4096L * 512);
  ctx_kernel<<<dim3(2, 8, 16), 1024, 0, stream>>>(kvT, wkdw, wvdw, par0, par1);
  // Q
  gemm_bt_kernel<<<dim3(32, 2, 16), 256, 0, stream>>>(xT, wq_bf, wq_bf, qT, 256,
                                                      4096L * 256, 4096L * 256);
  dwq_kernel<<<dim3(16, 8, 16), 256, 0, stream>>>(qT, wqdw, qp);
  // partials -> final ctx/ksum (placed in dead qT space; must run after dwq)
  reduce_kernel<<<dim3(128), 256, 0, stream>>>(par0, par1, ctxF, ksF);
  attn_kernel<<<dim3(32, 4, 16), 256, 0, stream>>>(qp, ctxF, ksF, sbuf);
  // O
  gemm_bt_kernel<<<dim3(32, 2, 16), 256, 0, stream>>>(sbuf, wo_bf, wo_bf, ybuf, 256,
                                                      4096L * 256, 4096L * 256);
  ln_tout_kernel<<<dim3(64, 16), 256, 0, stream>>>(ybuf, gout, out);
}

// Round 8
// 304.170 us; speedup vs baseline: 1.3354x; 1.0252x over previous
//
#include <hip/hip_runtime.h>

// LinearAttention (B=16, C=256, 64x64 spatial, 8 heads x 32) -- fp32 in/out, bf16/fp32 internal.
// Workspace map (byte offsets), peak 98 MiB:
//   par0  [0, 528K)              fp32 [128][1056]  ctx partials, strip 0 (live until attn)
//   wb    [528K, 1040K)          bf16 weights: wkv-interleaved (512x256) | wq | wo
//   par1  [1040K, 1568K)         fp32 [128][1056]  ctx partials, strip 1 (live until attn)
//   xT    [2 MiB, 34 MiB)        bf16 [16][4096][256]   LN(fmap)*g, transposed
//   kvT   [34 MiB, 98 MiB)       bf16 [16][4096][512]   k/v interleaved: col 2C=k_C, 2C+1=v_C
//                                LIVE during ctx -- nothing may alias it then! (R4 lesson)
//   qT    [34 MiB, 66 MiB)       alias (kvT dead after ctx)
//   q'    [66 MiB, 98 MiB)       softmaxed q
//   s     [2 MiB, 34 MiB)        silu(attn out)  (xT dead)
//   y     [66 MiB, 98 MiB)       s @ wo^T        (q' dead)
// Order: prep -> ln_tin -> gemm(KV) -> ctx -> gemm(Q) -> dwq -> attn(fused reduce) -> gemm(O) -> ln_tout
// R6 lesson: ctx is register-critical (+20 floats -> scratch spill). Packed-u32 prefetch only.
// R8: vectorized LN global access (scalar u16 was half-rate, 8x issues); reduce fused into attn.

typedef unsigned short u16;
typedef __bf16 bf16x8 __attribute__((ext_vector_type(8)));
typedef float f32x4 __attribute__((ext_vector_type(4)));
typedef float f32x16 __attribute__((ext_vector_type(16)));

#define DEV static __device__ __forceinline__

DEV float b2f(u16 u) { return __uint_as_float(((unsigned int)u) << 16); }
DEV u16 f2bf(float f) {
  unsigned int u = __float_as_uint(f);
  return (u16)((u + 0x7fffu + ((u >> 16) & 1u)) >> 16);  // RNE
}
DEV void gl2lds16(const void* g, void* l) {
  __builtin_amdgcn_global_load_lds((__attribute__((address_space(1))) void*)g,
                                   (__attribute__((address_space(3))) void*)l, 16, 0, 0);
}

// ---------------- prep: fp32 -> bf16 weight conversion (wk/wv row-interleaved) ----------
__global__ __launch_bounds__(256) void prep_kernel(const float* __restrict__ wk,
                                                   const float* __restrict__ wv,
                                                   const float* __restrict__ wq,
                                                   const float* __restrict__ wo,
                                                   u16* __restrict__ wb) {
  const int i = blockIdx.x * 256 + threadIdx.x;  // 0..65535
  const int yb = blockIdx.y;
  if (yb == 0)      wb[(i >> 8) * 512 + (i & 255)] = f2bf(wk[i]);        // row 2r
  else if (yb == 1) wb[(i >> 8) * 512 + 256 + (i & 255)] = f2bf(wv[i]);  // row 2r+1
  else if (yb == 2) wb[131072 + i] = f2bf(wq[i]);
  else              wb[196608 + i] = f2bf(wo[i]);
}

// ---------------- K0: channel-LN + transpose in (fp32 -> bf16) ----------------
// phase 1 unchanged (fp32 loads are full-rate coalesced); phase 3 vectorized:
// thread owns 8 contiguous channels -> uint4 xT stores (was 64 scalar u16 stores).
// tile stride 268 u16 (536 B): 8B-aligned b64 LDS reads in phase 3.
__global__ __launch_bounds__(256) void ln_tin_kernel(const float* __restrict__ f,
                                                     const float* __restrict__ g,
                                                     u16* __restrict__ xT) {
  __shared__ u16 tile[64 * 268];
  __shared__ float red[2 * 256];
  __shared__ float mu_s[64], inv_s[64];
  const int t = threadIdx.x;
  const int p0 = blockIdx.x * 64;
  const int b = blockIdx.y;
  const long fb = (long)b * 256 * 4096;
  const int p = t & 63, cg = t >> 6;
  float s1 = 0.f, s2 = 0.f;
  for (int pass = 0; pass < 64; ++pass) {
    int c = pass * 4 + cg;
    float v = f[fb + (long)c * 4096 + p0 + p];
    s1 += v; s2 += v * v;
    tile[p * 268 + c] = f2bf(v);
  }
  red[cg * 64 + p] = s1;
  red[256 + cg * 64 + p] = s2;
  __syncthreads();
  if (t < 64) {
    float a1 = red[t] + red[64 + t] + red[128 + t] + red[192 + t];
    float a2 = red[256 + t] + red[320 + t] + red[384 + t] + red[448 + t];
    float mu = a1 * (1.f / 256.f);
    float var = a2 * (1.f / 256.f) - mu * mu;
    mu_s[t] = mu;
    inv_s[t] = 1.0f / sqrtf(var + 1e-5f);
  }
  __syncthreads();
  {
    const int ch8 = (t & 31) * 8, wp = t >> 5;
    float ga[8];
#pragma unroll
    for (int e = 0; e < 8; ++e) ga[e] = g[ch8 + e];
#pragma unroll
    for (int pass = 0; pass < 8; ++pass) {
      const int px = pass * 8 + wp;
      uint2 lo = *(const uint2*)&tile[px * 268 + ch8];
      uint2 hi = *(const uint2*)&tile[px * 268 + ch8 + 4];
      const u16* sl = (const u16*)&lo;
      const u16* sh = (const u16*)&hi;
      const float mu = mu_s[px], inv = inv_s[px];
      uint4 o;
      u16* os = (u16*)&o;
#pragma unroll
      for (int e = 0; e < 4; ++e) os[e] = f2bf((b2f(sl[e]) - mu) * inv * ga[e]);
#pragma unroll
      for (int e = 0; e < 4; ++e) os[4 + e] = f2bf((b2f(sh[e]) - mu) * inv * ga[4 + e]);
      *(uint4*)&xT[((long)b * 4096 + p0 + px) * 256 + ch8] = o;
    }
  }
}

// ---------------- GEMM: C[m][n] = sum_k A[m][k]*Bt[n][k] (MFMA 16x16x32, 128x128 tile) ----
__global__ __launch_bounds__(256) void gemm_bt_kernel(
    const u16* __restrict__ A, const u16* __restrict__ B0, const u16* __restrict__ B1,
    u16* __restrict__ Cg, int ldc, long sA, long sC) {
  __shared__ u16 As[128 * 32];
  __shared__ u16 Bs[128 * 32];
  const int t = threadIdx.x;
  const int wave = t >> 6, lane = t & 63, quad = lane >> 4, l16 = lane & 15;
  const int wr = wave >> 1, wc = wave & 1;
  const int m0 = blockIdx.x * 128;
  const int jt = blockIdx.y;
  const int b = blockIdx.z;
  const u16* Ab = A + (long)b * sA + (long)m0 * 256;
  const u16* Bt = (jt < 2 ? B0 : B1) + (jt & 1) * 128 * 256;
  u16* Cb = Cg + (long)b * sC + (long)m0 * ldc + jt * 128;

  const int srow = lane >> 2;        // staging: row within 16-row chunk
  const int scol = (lane & 3) * 8;   // staging: col (elements)
  f32x4 acc[4][4];
#pragma unroll
  for (int i = 0; i < 4; ++i)
#pragma unroll
    for (int j = 0; j < 4; ++j) acc[i][j] = (f32x4){0.f, 0.f, 0.f, 0.f};

  const int aoff = (wr * 64 + l16) * 32 + quad * 8;
  const int boff = (wc * 64 + l16) * 32 + quad * 8;

  for (int ks = 0; ks < 8; ++ks) {
    const int k0 = ks * 32;
    __syncthreads();
    for (int i = wave; i < 8; i += 4) {
      gl2lds16(Ab + (i * 16 + srow) * 256 + k0 + scol, &As[i * 512 + lane * 8]);
      gl2lds16(Bt + (i * 16 + srow) * 256 + k0 + scol, &Bs[i * 512 + lane * 8]);
    }
    __syncthreads();  // compiler drains vmcnt(0) before s_barrier
    bf16x8 af[4], bfr[4];
#pragma unroll
    for (int mt = 0; mt < 4; ++mt) af[mt] = *(const bf16x8*)&As[aoff + mt * 512];
#pragma unroll
    for (int nt = 0; nt < 4; ++nt) bfr[nt] = *(const bf16x8*)&Bs[boff + nt * 512];
#pragma unroll
    for (int mt = 0; mt < 4; ++mt)
#pragma unroll
      for (int nt = 0; nt < 4; ++nt)
        acc[mt][nt] = __builtin_amdgcn_mfma_f32_16x16x32_bf16(af[mt], bfr[nt], acc[mt][nt], 0, 0, 0);
  }
#pragma unroll
  for (int mt = 0; mt < 4; ++mt) {
    const int mbase = wr * 64 + mt * 16 + quad * 4;
#pragma unroll
    for (int nt = 0; nt < 4; ++nt) {
      const int n = wc * 64 + nt * 16 + l16;
#pragma unroll
      for (int r = 0; r < 4; ++r)
        Cb[(long)(mbase + r) * ldc + n] = f2bf(acc[mt][nt][r]);
    }
  }
}

// ---------------- K2: dwconv(q) + softmax over d + *SCALE (LDS-tiled stencil) ----------
__global__ __launch_bounds__(256) void dwq_kernel(const u16* __restrict__ qT,
                                                  const float* __restrict__ wdw,
                                                  u16* __restrict__ qp) {
  __shared__ u16 tile[6 * 66 * 40];  // [slot][y+1][ch pad40], 31680 B
  const int t = threadIdx.x;
  const int strip = blockIdx.x, h = blockIdx.y, b = blockIdx.z;
  const int x0 = strip * 4;
  const int wave = t >> 6, lane = t & 63;
  const int ysel = lane & 15, cg = lane >> 4;
  const int y = wave * 16 + ysel;
  const int ty = t >> 2, tc = t & 3;  // staging: y-row, ch-quarter

  // zero y-borders (rows 0 and 65 of each slot)
  if (t < 48) {
    const int slot = t >> 3, brd = (t >> 2) & 1, c4 = t & 3;
    *(uint4*)&tile[slot * 2640 + (brd ? 65 * 40 : 0) + c4 * 8] = (uint4){0, 0, 0, 0};
  }
  // stage rows x0-1 .. x0+4 (zeros when out of range)
  const u16* qrow = qT + (long)b * 4096 * 256 + h * 32 + tc * 8;
#pragma unroll
  for (int s = 0; s < 6; ++s) {
    const int xx = x0 - 1 + s;
    uint4 v = (uint4){0, 0, 0, 0};
    if ((unsigned)xx < 64u) v = *(const uint4*)(qrow + (long)(xx * 64 + ty) * 256);
    *(uint4*)&tile[s * 2640 + (ty + 1) * 40 + tc * 8] = v;
  }
  float w[72];
#pragma unroll
  for (int q = 0; q < 8; ++q)
#pragma unroll
    for (int i = 0; i < 9; ++i) w[q * 9 + i] = wdw[(h * 32 + cg * 8 + q) * 9 + i];
  __syncthreads();

  u16* ob = qp + ((long)b * 4096 + y) * 256 + h * 32 + cg * 8;
#pragma unroll
  for (int it = 0; it < 4; ++it) {
    const int x = x0 + it;
    float acc[8] = {0.f, 0.f, 0.f, 0.f, 0.f, 0.f, 0.f, 0.f};
#pragma unroll
    for (int r = 0; r < 3; ++r) {
#pragma unroll
      for (int dy = 0; dy < 3; ++dy) {
        uint4 pk = *(const uint4*)&tile[(it + r) * 2640 + (y + dy) * 40 + cg * 8];
        const u16* s = (const u16*)&pk;
#pragma unroll
        for (int q = 0; q < 8; ++q)
          acc[q] = fmaf(w[q * 9 + r * 3 + dy], b2f(s[q]), acc[q]);
      }
    }
    float e[8];
    float s = 0.f;
#pragma unroll
    for (int q = 0; q < 8; ++q) { e[q] = __expf(acc[q]); s += e[q]; }
    s += __shfl_xor(s, 16);
    s += __shfl_xor(s, 32);
    const float inv = 0.17677669529663687f / s;  // SCALE / sum
    uint4 o;
    u16* os = (u16*)&o;
#pragma unroll
    for (int q = 0; q < 8; ++q) os[q] = f2bf(e[q] * inv);
    *(uint4*)(ob + (long)x * 16384) = o;
  }
}

// ---------------- K3: dwconv(k,v)+exp + Gram via 32x32x16 MFMA (packed-prefetch streamer)
__global__ __launch_bounds__(1024, 4) void ctx_kernel(const u16* __restrict__ kvT,
                                                      const float* __restrict__ wkdw,
                                                      const float* __restrict__ wvdw,
                                                      float* __restrict__ par0,
                                                      float* __restrict__ par1) {
  __shared__ float redb[8 * 1088];  // 34816 B: staging slabs for the wave tree
  __shared__ float redk[16 * 32];   // per-wave ksum partials
  const int t = threadIdx.x;
  const int strip = blockIdx.x, h = blockIdx.y, b = blockIdx.z;
  const int wave = t >> 6, lane = t & 63;
  const int g = wave >> 2, wq = wave & 3;
  const int x0 = strip * 32 + g * 8;
  const int c = lane & 31, half = lane >> 5;
  const int ystart = wq * 16 + half * 8;
  float wk[9], wv[9];
#pragma unroll
  for (int i = 0; i < 9; ++i) {
    wk[i] = wkdw[(h * 32 + c) * 9 + i];
    wv[i] = wvdw[(h * 32 + c) * 9 + i];
  }
  const u16* kb = kvT + (long)b * 4096 * 512 + 2 * (h * 32 + c);

  float fk[3][10], fv[3][10];  // rows x-1, x, x+1 (unpacked)
  unsigned pk[10];             // packed prefetch (row x+2): 10 regs only
#pragma unroll
  for (int r = 0; r < 2; ++r) {
    const int x = x0 - 1 + r;
#pragma unroll
    for (int m = 0; m < 10; ++m) {
      const int yy = ystart - 1 + m;
      float a = 0.f, bb = 0.f;
      if (((unsigned)x < 64u) & ((unsigned)yy < 64u)) {
        const unsigned u = *(const unsigned*)(kb + (long)(x * 64 + yy) * 512);
        a = b2f((u16)(u & 0xffffu));
        bb = b2f((u16)(u >> 16));
      }
      fk[r][m] = a; fv[r][m] = bb;
    }
  }
  // row x0+1 packed, then unpack into window slot 2
#pragma unroll
  for (int m = 0; m < 10; ++m) {
    const int yy = ystart - 1 + m;
    unsigned u = 0;
    if (((unsigned)(x0 + 1) < 64u) & ((unsigned)yy < 64u))
      u = *(const unsigned*)(kb + (long)((x0 + 1) * 64 + yy) * 512);
    pk[m] = u;
  }
#pragma unroll
  for (int m = 0; m < 10; ++m) {
    fk[2][m] = __uint_as_float(pk[m] << 16);
    fv[2][m] = __uint_as_float(pk[m] & 0xffff0000u);
  }
  f32x16 acc;
#pragma unroll
  for (int r = 0; r < 16; ++r) acc[r] = 0.f;
  float ks = 0.f;

  for (int it = 0; it < 8; ++it) {
    // 1) prefetch row x+2 PACKED (first use is step 3 -- full stencil hides latency)
    const int xn = x0 + it + 2;
#pragma unroll
    for (int m = 0; m < 10; ++m) {
      const int yy = ystart - 1 + m;
      unsigned u = 0;
      if (((unsigned)xn < 64u) & ((unsigned)yy < 64u))
        u = *(const unsigned*)(kb + (long)(xn * 64 + yy) * 512);
      pk[m] = u;
    }
    // 2) stencil + exp + MFMA on the unpacked window (independent of pk)
    union { bf16x8 v; u16 s[8]; } af, bf_;
#pragma unroll
    for (int j = 0; j < 8; ++j) {
      float a = 0.f, bb = 0.f;
#pragma unroll
      for (int r = 0; r < 3; ++r)
#pragma unroll
        for (int dy = 0; dy < 3; ++dy) {
          a = fmaf(wk[r * 3 + dy], fk[r][j + dy], a);
          bb = fmaf(wv[r * 3 + dy], fv[r][j + dy], bb);
        }
      const u16 eb = f2bf(__expf(a));
      ks += b2f(eb);
      af.s[j] = eb;
      bf_.s[j] = f2bf(bb);
    }
    acc = __builtin_amdgcn_mfma_f32_32x32x16_bf16(af.v, bf_.v, acc, 0, 0, 0);
    // 3) shift window; unpack prefetched row into slot 2 (bit-identical to b2f lo/hi)
#pragma unroll
    for (int m = 0; m < 10; ++m) {
      fk[0][m] = fk[1][m]; fv[0][m] = fv[1][m];
      fk[1][m] = fk[2][m]; fv[1][m] = fv[2][m];
      fk[2][m] = __uint_as_float(pk[m] << 16);
      fv[2][m] = __uint_as_float(pk[m] & 0xffff0000u);
    }
  }
  // ksum: combine y-halves (same c), stage per wave
  ks += __shfl_xor(ks, 32);
  if (half == 0) redk[wave * 32 + c] = ks;
  // 3-round tree reduction of the 16 wave accumulators (LDS stays at 8 slabs):
  if (wave >= 8) {
#pragma unroll
    for (int r = 0; r < 16; ++r) redb[(wave - 8) * 1088 + lane * 17 + r] = acc[r];
  }
  __syncthreads();
  if (wave < 8) {
#pragma unroll
    for (int r = 0; r < 16; ++r) acc[r] += redb[wave * 1088 + lane * 17 + r];
  }
  __syncthreads();
  if (wave >= 4 && wave < 8) {
#pragma unroll
    for (int r = 0; r < 16; ++r) redb[(wave - 4) * 1088 + lane * 17 + r] = acc[r];
  }
  __syncthreads();
  if (wave < 4) {
#pragma unroll
    for (int r = 0; r < 16; ++r) acc[r] += redb[wave * 1088 + lane * 17 + r];
  }
  __syncthreads();
  if (wave >= 1 && wave < 4) {
#pragma unroll
    for (int r = 0; r < 16; ++r) redb[(wave - 1) * 1088 + lane * 17 + r] = acc[r];
  }
  __syncthreads();
  if (wave == 0) {
    float* par = (strip ? par1 : par0) + (long)(b * 8 + h) * 1056;
#pragma unroll
    for (int r = 0; r < 16; ++r) {
      float sum = acc[r] + redb[lane * 17 + r] + redb[1088 + lane * 17 + r] +
                  redb[2176 + lane * 17 + r];
      const int d = (r & 3) + 8 * (r >> 2) + 4 * half;  // C/D row map [m74/m101]
      par[d * 32 + c] = sum;  // plain coalesced store -- no atomic
    }
    if (t < 32) {
      float s = 0.f;
#pragma unroll
      for (int w = 0; w < 16; ++w) s += redk[w * 32 + t];
      par[1024 + t] = s;
    }
  }
}

// ---------------- K4: s = silu(q' @ (ctx/ksum)) via MFMA 16x16x32, fused strip-reduce ---
// block = (128-row tile, head-pair, batch), 256 threads = 4 waves x 32 rows.
// Prologue: sums par0+par1 (gram + ksum) inline, normalizes, bf16 hi+lo split in LDS.
// Main: per head, per 16-row tile: A-frag straight from global q' (16 B/lane),
// D = A*cn_lo + A*cn_hi (chained MFMA, fp32-accurate cn). Epilogue: silu + store.
__global__ __launch_bounds__(256) void attn_kernel(const u16* __restrict__ qp,
                                                   const float* __restrict__ par0,
                                                   const float* __restrict__ par1,
                                                   u16* __restrict__ sout) {
  __shared__ u16 cnhi[2 * 32 * 40];  // [hh][e][d], 5120 B
  __shared__ u16 cnlo[2 * 32 * 40];
  const int t = threadIdx.x;
  const int p0 = blockIdx.x * 128;
  const int hp = blockIdx.y;  // head pair
  const int b = blockIdx.z;
  const int wave = t >> 6, lane = t & 63, quad = lane >> 4, l16 = lane & 15;

  // fused reduce: ctx = par0+par1, ksum = par0k+par1k; normalize, split hi/lo, transpose
  for (int j = 0; j < 8; ++j) {
    const int lidx = j * 256 + t;  // [0,2048)
    const int e = lidx & 31, d = (lidx >> 5) & 31, hh = lidx >> 10;
    const long base = (long)(b * 8 + hp * 2 + hh) * 1056;
    const float ks = par0[base + 1024 + d] + par1[base + 1024 + d];
    const float c = (par0[base + d * 32 + e] + par1[base + d * 32 + e]) / ks;
    const u16 hi = f2bf(c);
    cnhi[hh * 1280 + e * 40 + d] = hi;
    cnlo[hh * 1280 + e * 40 + d] = f2bf(c - b2f(hi));
  }
  __syncthreads();

  const u16* qb = qp + ((long)b * 4096 + p0 + wave * 32) * 256;
  u16* ob = sout + ((long)b * 4096 + p0 + wave * 32) * 256;
#pragma unroll
  for (int hh = 0; hh < 2; ++hh) {
    const int h = hp * 2 + hh;
    const int cb = hh * 1280 + quad * 8;
    const bf16x8 bhi0 = *(const bf16x8*)&cnhi[cb + l16 * 40];
    const bf16x8 bhi1 = *(const bf16x8*)&cnhi[cb + (16 + l16) * 40];
    const bf16x8 blo0 = *(const bf16x8*)&cnlo[cb + l16 * 40];
    const bf16x8 blo1 = *(const bf16x8*)&cnlo[cb + (16 + l16) * 40];
#pragma unroll
    for (int rt = 0; rt < 2; ++rt) {
      const bf16x8 af = *(const bf16x8*)&qb[(rt * 16 + l16) * 256 + h * 32 + quad * 8];
      f32x4 a0 = (f32x4){0.f, 0.f, 0.f, 0.f};
      f32x4 a1 = (f32x4){0.f, 0.f, 0.f, 0.f};
      a0 = __builtin_amdgcn_mfma_f32_16x16x32_bf16(af, blo0, a0, 0, 0, 0);
      a0 = __builtin_amdgcn_mfma_f32_16x16x32_bf16(af, bhi0, a0, 0, 0, 0);
      a1 = __builtin_amdgcn_mfma_f32_16x16x32_bf16(af, blo1, a1, 0, 0, 0);
      a1 = __builtin_amdgcn_mfma_f32_16x16x32_bf16(af, bhi1, a1, 0, 0, 0);
#pragma unroll
      for (int r = 0; r < 4; ++r) {
        const int row = rt * 16 + quad * 4 + r;
        const float v0 = a0[r], v1 = a1[r];
        ob[(long)row * 256 + h * 32 + l16] = f2bf(v0 / (1.f + __expf(-v0)));
        ob[(long)row * 256 + h * 32 + 16 + l16] = f2bf(v1 / (1.f + __expf(-v1)));
      }
    }
  }
}

// ---------------- K6: channel-LN + transpose out (bf16 -> fp32) ----------------
// phase 1: per-pixel stats from CONTIGUOUS uint4 loads (channels contiguous in y) --
// was 64 scalar u16 loads/thread. tile stride 268 u16 (536 B, 8B-aligned b64 access).
// phase 3: b64 LDS read of 4 channels, 4 coalesced dword stores (unchanged pattern).
__global__ __launch_bounds__(256) void ln_tout_kernel(const u16* __restrict__ y,
                                                      const float* __restrict__ gout,
                                                      float* __restrict__ out) {
  __shared__ u16 tile[64 * 268];
  __shared__ float red[2 * 256];
  __shared__ float mu_s[64], inv_s[64];
  const int t = threadIdx.x;
  const int p0 = blockIdx.x * 64;
  const int b = blockIdx.y;
  // phase 1: thread -> (pixel px = t>>2, quarter q = t&3); 8 uint4 loads, interleaved ch
  {
    const int px = t >> 2, q = t & 3;
    const u16* yrow = y + ((long)b * 4096 + p0 + px) * 256;
    float s1 = 0.f, s2 = 0.f;
#pragma unroll
    for (int j = 0; j < 8; ++j) {
      const int ch = q * 8 + j * 32;
      uint4 v = *(const uint4*)&yrow[ch];
      const u16* s = (const u16*)&v;
#pragma unroll
      for (int e = 0; e < 8; ++e) {
        float fv = b2f(s[e]);
        s1 += fv; s2 += fv * fv;
      }
      *(uint2*)&tile[px * 268 + ch] = (uint2){v.x, v.y};
      *(uint2*)&tile[px * 268 + ch + 4] = (uint2){v.z, v.w};
    }
    red[q * 64 + px] = s1;
    red[256 + q * 64 + px] = s2;
  }
  __syncthreads();
  if (t < 64) {
    float s1 = red[t] + red[64 + t] + red[128 + t] + red[192 + t];
    float s2 = red[256 + t] + red[320 + t] + red[384 + t] + red[448 + t];
    float mu = s1 * (1.f / 256.f);
    float var = s2 * (1.f / 256.f) - mu * mu;
    mu_s[t] = mu;
    inv_s[t] = 1.0f / sqrtf(var + 1e-5f);
  }
  __syncthreads();
  // phase 3: wave cw handles channel slice c4 = pass*16 + cw*4; lane = pixel
  {
    const int lpx = t & 63, cw = t >> 6;
    const long ob = (long)b * 256 * 4096;
    const float mu = mu_s[lpx], inv = inv_s[lpx];
#pragma unroll
    for (int pass = 0; pass < 16; ++pass) {
      const int c4 = pass * 16 + cw * 4;
      uint2 v = *(const uint2*)&tile[lpx * 268 + c4];
      const u16* s = (const u16*)&v;
#pragma unroll
      for (int i = 0; i < 4; ++i)
        out[ob + (long)(c4 + i) * 4096 + p0 + lpx] = (b2f(s[i]) - mu) * inv * gout[c4 + i];
    }
  }
}

extern "C" void kernel_launch(void* const* d_in, const int* in_sizes, int n_in,
                              void* d_out, int out_size, void* d_ws, size_t ws_size,
                              hipStream_t stream) {
  (void)in_sizes; (void)n_in; (void)out_size; (void)ws_size;
  const float* fmap = (const float*)d_in[0];
  const float* gnorm = (const float*)d_in[1];
  const float* wq1 = (const float*)d_in[2];
  const float* wqdw = (const float*)d_in[3];
  const float* wk1 = (const float*)d_in[4];
  const float* wkdw = (const float*)d_in[5];
  const float* wv1 = (const float*)d_in[6];
  const float* wvdw = (const float*)d_in[7];
  const float* wo = (const float*)d_in[8];
  const float* gout = (const float*)d_in[9];
  float* out = (float*)d_out;
  char* ws = (char*)d_ws;

  float* par0 = (float*)(ws);                    // [0, 528K)  128*1056*4, live until attn
  u16* wb = (u16*)(ws + 540672);                 // [528K, 1040K) bf16 wkv|wq|wo
  float* par1 = (float*)(ws + 1064960);          // [1040K, 1568K), live until attn
  u16* wkv_bf = wb;                              // interleaved 512x256
  u16* wq_bf = wb + 131072;
  u16* wo_bf = wb + 196608;
  u16* xT = (u16*)(ws + 2097152);                // [2, 34) MiB
  u16* kvT = (u16*)(ws + 35651584);              // [34, 98) MiB -- live through ctx
  u16* qT = kvT;                                 // alias (kvT dead after ctx)
  u16* qp = (u16*)(ws + 69206016);               // [66, 98) MiB (written only after ctx)
  u16* sbuf = xT;                                // alias (xT dead after Q gemm)
  u16* ybuf = qp;                                // alias (qp dead after attn)

  prep_kernel<<<dim3(256, 4), 256, 0, stream>>>(wk1, wv1, wq1, wo, wb);
  ln_tin_kernel<<<dim3(64, 16), 256, 0, stream>>>(fmap, gnorm, xT);
  // KV interleaved: col 2C = k_C, col 2C+1 = v_C (wkv rows interleaved by prep)
  gemm_bt_kernel<<<dim3(32, 4, 16), 256, 0, stream>>>(xT, wkv_bf, wkv_bf + 65536, kvT, 512,
                                                      4096L * 256, 4096L * 512);
  ctx_kernel<<<dim3(2, 8, 16), 1024, 0, stream>>>(kvT, wkdw, wvdw, par0, par1);
  // Q
  gemm_bt_kernel<<<dim3(32, 2, 16), 256, 0, stream>>>(xT, wq_bf, wq_bf, qT, 256,
                                                      4096L * 256, 4096L * 256);
  dwq_kernel<<<dim3(16, 8, 16), 256, 0, stream>>>(qT, wqdw, qp);
  // attn with fused strip-reduce (reads par0/par1 directly; reduce_kernel removed)
  attn_kernel<<<dim3(32, 4, 16), 256, 0, stream>>>(qp, par0, par1, sbuf);
  // O
  gemm_bt_kernel<<<dim3(32, 2, 16), 256, 0, stream>>>(sbuf, wo_bf, wo_bf, ybuf, 256,
                                                      4096L * 256, 4096L * 256);
  ln_tout_kernel<<<dim3(64, 16), 256, 0, stream>>>(ybuf, gout, out);
}